// Round 2
// baseline (1470.315 us; speedup 1.0000x reference)
//
#include <hip/hip_runtime.h>

// ---------------------------------------------------------------------------
// Self-attention (B=4, S=4096, D=1024), fp32 in/out.
// Precision strategy: logits are unscaled (sigma~32) so softmax is near-argmax
// and bf16 logit noise (~0.2) flips near-tie rows (R1: absmax 0.84). Fix:
// double-bf16 ("split") arithmetic on the Q/K chain: every fp32 operand is
// hi+lo bf16 (lo = bf16(x - hi), ~2^-16 rel), GEMM = 3 MFMA terms
// (hi*hi + hi*lo + lo*hi). Q/K projections and QK^T use split; V projection
// and PV use single bf16 (linear error ~0.004 << 0.108 threshold).
// ---------------------------------------------------------------------------

#define BM 128
#define BN 128
#define BK 32
#define LDST 40   // padded LDS row stride (elems); 80B = 16B-aligned

typedef __attribute__((ext_vector_type(4))) float floatx4;
typedef __attribute__((ext_vector_type(8))) short shortx8;
typedef unsigned short ushort_t;

__device__ __forceinline__ ushort_t f2bf(float f) {
  union { float f; unsigned u; } x; x.f = f;
  unsigned r = x.u + 0x7fffu + ((x.u >> 16) & 1u);  // RNE
  return (ushort_t)(r >> 16);
}
__device__ __forceinline__ float bf2f(ushort_t h) {
  union { unsigned u; float f; } x; x.u = ((unsigned)h) << 16; return x.f;
}

// AMODE: 0 = A fp32 global -> bf16 hi only; 1 = A fp32 -> split hi/lo;
//        2 = A is two bf16 global arrays (pre-split pair)
// BMODE: 0 = B single bf16; 1 = B bf16 pair
// OMODE: 0 = C fp32 [row*ldc+col]; 1 = C bf16 pair [row*ldc+col];
//        2 = C bf16 single, per-batch transposed [b*bstride + col*ldc + (row&4095)]
template<int AMODE, int BMODE, int OMODE>
__global__ __launch_bounds__(256)
void gemm_bt(const void* __restrict__ A0v, const void* __restrict__ A1v,
             const ushort_t* __restrict__ B0, const ushort_t* __restrict__ B1,
             void* __restrict__ C0v, void* __restrict__ C1v,
             int K, int ldc, long bstride)
{
  constexpr int NA = (AMODE == 0) ? 1 : 2;
  constexpr int NB = (BMODE == 0) ? 1 : 2;
  constexpr bool DUAL = (AMODE != 0) && (BMODE == 1);
  __shared__ ushort_t As[NA][BM][LDST];
  __shared__ ushort_t Bs[NB][BN][LDST];

  const int tid = threadIdx.x;
  const long row0 = (long)blockIdx.x * BM;
  const long col0 = (long)blockIdx.y * BN;
  const int wid = tid >> 6, lane = tid & 63;
  const int wm = (wid >> 1) * 64, wn = (wid & 1) * 64;
  const int lr = lane & 15, lq = lane >> 4;

  floatx4 acc[4][4] = {};

  for (int k0 = 0; k0 < K; k0 += BK) {
    // ---- stage A ----
    if constexpr (AMODE <= 1) {
      const float* A = (const float*)A0v;
#pragma unroll
      for (int j = 0; j < 4; ++j) {
        int idx = tid + j * 256;                   // 1024 float4 loads
        int r = idx >> 3, c = (idx & 7) * 4;
        float4 v = *(const float4*)(A + (row0 + r) * (long)K + k0 + c);
        ushort_t h0 = f2bf(v.x), h1 = f2bf(v.y), h2 = f2bf(v.z), h3 = f2bf(v.w);
        ushort_t* d = &As[0][r][c];
        d[0] = h0; d[1] = h1; d[2] = h2; d[3] = h3;
        if constexpr (AMODE == 1) {
          ushort_t* e = &As[1][r][c];
          e[0] = f2bf(v.x - bf2f(h0)); e[1] = f2bf(v.y - bf2f(h1));
          e[2] = f2bf(v.z - bf2f(h2)); e[3] = f2bf(v.w - bf2f(h3));
        }
      }
    } else {
      const ushort_t* A0 = (const ushort_t*)A0v;
      const ushort_t* A1 = (const ushort_t*)A1v;
#pragma unroll
      for (int j = 0; j < 2; ++j) {
        int idx = tid + j * 256;                   // 512 16B loads each
        int r = idx >> 2, c = (idx & 3) * 8;
        *(uint4*)&As[0][r][c] = *(const uint4*)(A0 + (row0 + r) * (long)K + k0 + c);
        *(uint4*)&As[1][r][c] = *(const uint4*)(A1 + (row0 + r) * (long)K + k0 + c);
      }
    }
    // ---- stage B ----
#pragma unroll
    for (int j = 0; j < 2; ++j) {
      int idx = tid + j * 256;
      int r = idx >> 2, c = (idx & 3) * 8;
      *(uint4*)&Bs[0][r][c] = *(const uint4*)(B0 + (col0 + r) * (long)K + k0 + c);
      if constexpr (BMODE == 1)
        *(uint4*)&Bs[1][r][c] = *(const uint4*)(B1 + (col0 + r) * (long)K + k0 + c);
    }
    __syncthreads();

    shortx8 ah[4], al[4], bh[4], bl[4];
#pragma unroll
    for (int t = 0; t < 4; ++t) {
      ah[t] = *(const shortx8*)&As[0][wm + t * 16 + lr][lq * 8];
      bh[t] = *(const shortx8*)&Bs[0][wn + t * 16 + lr][lq * 8];
      if constexpr (NA == 2) al[t] = *(const shortx8*)&As[1][wm + t * 16 + lr][lq * 8];
      if constexpr (NB == 2) bl[t] = *(const shortx8*)&Bs[1][wn + t * 16 + lr][lq * 8];
    }
#pragma unroll
    for (int mt = 0; mt < 4; ++mt)
#pragma unroll
      for (int nt = 0; nt < 4; ++nt) {
        acc[mt][nt] = __builtin_amdgcn_mfma_f32_16x16x32_bf16(ah[mt], bh[nt], acc[mt][nt], 0, 0, 0);
        if constexpr (DUAL) {
          acc[mt][nt] = __builtin_amdgcn_mfma_f32_16x16x32_bf16(ah[mt], bl[nt], acc[mt][nt], 0, 0, 0);
          acc[mt][nt] = __builtin_amdgcn_mfma_f32_16x16x32_bf16(al[mt], bh[nt], acc[mt][nt], 0, 0, 0);
        }
      }
    __syncthreads();
  }

  // C/D layout (verified m89/m91): col = lane&15, row = (lane>>4)*4 + reg
#pragma unroll
  for (int mt = 0; mt < 4; ++mt) {
#pragma unroll
    for (int nt = 0; nt < 4; ++nt) {
      long col = col0 + wn + nt * 16 + lr;
#pragma unroll
      for (int r = 0; r < 4; ++r) {
        long row = row0 + wm + mt * 16 + lq * 4 + r;
        float v = acc[mt][nt][r];
        if constexpr (OMODE == 0) {
          ((float*)C0v)[row * ldc + col] = v;
        } else if constexpr (OMODE == 1) {
          ushort_t h = f2bf(v);
          ((ushort_t*)C0v)[row * ldc + col] = h;
          ((ushort_t*)C1v)[row * ldc + col] = f2bf(v - bf2f(h));
        } else {
          long b = row >> 12, s = row & 4095;    // S = 4096
          ((ushort_t*)C0v)[b * bstride + col * ldc + s] = f2bf(v);
        }
      }
    }
  }
}

__global__ __launch_bounds__(256)
void cast_w_split(const float* __restrict__ in, ushort_t* __restrict__ hi,
                  ushort_t* __restrict__ lo, int n4) {
  int i = blockIdx.x * 256 + threadIdx.x;
  if (i < n4) {
    float4 v = ((const float4*)in)[i];
    ushort4 h, l;
    h.x = f2bf(v.x); l.x = f2bf(v.x - bf2f(h.x));
    h.y = f2bf(v.y); l.y = f2bf(v.y - bf2f(h.y));
    h.z = f2bf(v.z); l.z = f2bf(v.z - bf2f(h.z));
    h.w = f2bf(v.w); l.w = f2bf(v.w - bf2f(h.w));
    ((ushort4*)hi)[i] = h;
    ((ushort4*)lo)[i] = l;
  }
}

// In-place masked softmax over one row of 4096 fp32 scores per block.
__global__ __launch_bounds__(256)
void softmax_rows(float* __restrict__ scores, const int* __restrict__ length, int b) {
  const int S = 4096;
  float* p = scores + (long)blockIdx.x * S;
  const int sent = length[b] * 2;
  const int tid = threadIdx.x;
  float vals[16];
  float mx = -3.4e38f;
#pragma unroll
  for (int j = 0; j < 16; ++j) {
    int c = tid + j * 256;
    float v = p[c];
    v = (c < sent) ? v : -2147483648.0f;   // NEG_BIG
    vals[j] = v;
    mx = fmaxf(mx, v);
  }
#pragma unroll
  for (int off = 32; off > 0; off >>= 1) mx = fmaxf(mx, __shfl_down(mx, off));
  __shared__ float red[8];
  if ((tid & 63) == 0) red[tid >> 6] = mx;
  __syncthreads();
  mx = fmaxf(fmaxf(red[0], red[1]), fmaxf(red[2], red[3]));
  float sum = 0.f;
#pragma unroll
  for (int j = 0; j < 16; ++j) { vals[j] = __expf(vals[j] - mx); sum += vals[j]; }
#pragma unroll
  for (int off = 32; off > 0; off >>= 1) sum += __shfl_down(sum, off);
  __syncthreads();
  if ((tid & 63) == 0) red[tid >> 6] = sum;
  __syncthreads();
  float inv = 1.0f / (red[0] + red[1] + red[2] + red[3]);
#pragma unroll
  for (int j = 0; j < 16; ++j) p[tid + j * 256] = vals[j] * inv;
}

extern "C" void kernel_launch(void* const* d_in, const int* in_sizes, int n_in,
                              void* d_out, int out_size, void* d_ws, size_t ws_size,
                              hipStream_t stream) {
  const float* X   = (const float*)d_in[0];   // [4,4096,1024]
  const int*   len = (const int*)d_in[1];     // [4]
  const float* Wq  = (const float*)d_in[2];   // [1024,1024]
  const float* Wk  = (const float*)d_in[3];
  const float* Wv  = (const float*)d_in[4];
  float* out = (float*)d_out;

  const int Bn = 4, S = 4096, D = 1024;
  const long MS = (long)Bn * S;               // 16384

  char* w = (char*)d_ws;
  ushort_t* Qhi = (ushort_t*)w; w += MS * D * 2;
  ushort_t* Qlo = (ushort_t*)w; w += MS * D * 2;
  ushort_t* Khi = (ushort_t*)w; w += MS * D * 2;
  ushort_t* Klo = (ushort_t*)w; w += MS * D * 2;
  ushort_t* Vt  = (ushort_t*)w; w += MS * D * 2;        // bf16 [B][D][S]
  ushort_t* Wqh = (ushort_t*)w; w += (long)D * D * 2;
  ushort_t* Wql = (ushort_t*)w; w += (long)D * D * 2;
  ushort_t* Wkh = (ushort_t*)w; w += (long)D * D * 2;
  ushort_t* Wkl = (ushort_t*)w; w += (long)D * D * 2;
  ushort_t* Wvh = (ushort_t*)w; w += (long)D * D * 2;
  ushort_t* Wvl = (ushort_t*)w; w += (long)D * D * 2;
  float*    sc  = (float*)w;    w += (long)S * S * 4;   // fp32 [4096][4096]

  const int n4 = D * D / 4;
  cast_w_split<<<(n4 + 255) / 256, 256, 0, stream>>>(Wq, Wqh, Wql, n4);
  cast_w_split<<<(n4 + 255) / 256, 256, 0, stream>>>(Wk, Wkh, Wkl, n4);
  cast_w_split<<<(n4 + 255) / 256, 256, 0, stream>>>(Wv, Wvh, Wvl, n4);

  dim3 blk(256);
  dim3 gproj(MS / BM, D / BN);                // (128, 8)
  // Q, K projections: fp32 X split in LDS, split weights, split output pair
  gemm_bt<1, 1, 1><<<gproj, blk, 0, stream>>>(X, nullptr, Wqh, Wql, Qhi, Qlo, D, D, 0);
  gemm_bt<1, 1, 1><<<gproj, blk, 0, stream>>>(X, nullptr, Wkh, Wkl, Khi, Klo, D, D, 0);
  // V projection: single bf16, transposed per batch
  gemm_bt<0, 0, 2><<<gproj, blk, 0, stream>>>(X, nullptr, Wvh, nullptr, Vt, nullptr,
                                              D, S, (long)D * S);

  for (int b = 0; b < Bn; ++b) {
    const long so = (long)b * S * D;
    // QK^T in double-bf16 (3-term MFMA), fp32 scores
    gemm_bt<2, 1, 0><<<dim3(S / BM, S / BN), blk, 0, stream>>>(
        Qhi + so, Qlo + so, Khi + so, Klo + so, sc, nullptr, D, S, 0);
    softmax_rows<<<S, 256, 0, stream>>>(sc, len, b);
    // PV: P fp32 -> bf16 hi in LDS, Vt single bf16
    gemm_bt<0, 0, 0><<<dim3(S / BM, D / BN), blk, 0, stream>>>(
        sc, nullptr, Vt + (long)b * D * S, nullptr, out + so, nullptr, S, D, 0);
  }
}

// Round 3
// 1027.555 us; speedup vs baseline: 1.4309x; 1.4309x over previous
//
#include <hip/hip_runtime.h>

// ---------------------------------------------------------------------------
// Self-attention (B=4, S=4096, D=1024), fp32 in/out.
// Precision: dual-bf16 (hi+lo split, 3-term MFMA) on the Q/K chain — logits
// are unscaled (sigma~32, near-argmax softmax), single-bf16 logit noise flips
// near-tie rows (R1). V / PV single-bf16 (linear error ~0.006 << 0.108 thr).
// R3: length-aware exact skipping (masked keys are provably unused),
// batch-z dispatches for QK^T/softmax/PV when ws allows (4x fp32 scores),
// packed 8B stores in the V-transpose epilogue.
// ---------------------------------------------------------------------------

#define BM 128
#define BN 128
#define BK 32
#define LDST 40   // padded LDS row stride (elems); 80B = 16B-aligned

typedef __attribute__((ext_vector_type(4))) float floatx4;
typedef __attribute__((ext_vector_type(8))) short shortx8;
typedef unsigned short ushort_t;

__device__ __forceinline__ ushort_t f2bf(float f) {
  union { float f; unsigned u; } x; x.f = f;
  unsigned r = x.u + 0x7fffu + ((x.u >> 16) & 1u);  // RNE
  return (ushort_t)(r >> 16);
}
__device__ __forceinline__ float bf2f(ushort_t h) {
  union { unsigned u; float f; } x; x.u = ((unsigned)h) << 16; return x.f;
}

// AMODE: 0 = A fp32 -> bf16 hi only; 1 = A fp32 -> split hi/lo in LDS;
//        2 = A is two bf16 global arrays (pre-split pair)
// BMODE: 0 = B single bf16; 1 = B bf16 pair
// OMODE: 0 = C fp32 [row*ldc+col]; 1 = C bf16 pair [row*ldc+col];
//        2 = C bf16 single, per-batch transposed [b*bstride + col*ldc + (row&4095)]
// LMODE: 0 = none; 1 = skip block if col0 >= sent (QK^T);
//        2 = K-loop bound = roundup(sent,128) (PV);
//        3 = skip block if (row0&4095) >= roundup(sent,128) (K/V proj)
template<int AMODE, int BMODE, int OMODE, int LMODE>
__global__ __launch_bounds__(256)
void gemm_bt(const void* __restrict__ A0v, const void* __restrict__ A1v,
             const ushort_t* __restrict__ B0g, const ushort_t* __restrict__ B1g,
             void* __restrict__ C0v, void* __restrict__ C1v,
             int K, int ldc, long bstride,
             const int* __restrict__ lenp, int b0, long sA, long sB, long sC)
{
  constexpr int NA = (AMODE == 0) ? 1 : 2;
  constexpr int NB = (BMODE == 0) ? 1 : 2;
  constexpr bool DUAL = (AMODE != 0) && (BMODE == 1);
  __shared__ ushort_t As[NA][BM][LDST];
  __shared__ ushort_t Bs[NB][BN][LDST];

  const int tid = threadIdx.x;
  const long row0 = (long)blockIdx.x * BM;
  const long col0 = (long)blockIdx.y * BN;
  const int b = b0 + blockIdx.z;

  int kend = K;
  if constexpr (LMODE == 1 || LMODE == 2) {
    const int sent = lenp[b] * 2;
    if constexpr (LMODE == 1) { if (col0 >= sent) return; }
    else kend = (sent + 127) & ~127;
  } else if constexpr (LMODE == 3) {
    const int sent = lenp[row0 >> 12] * 2;
    if ((int)(row0 & 4095) >= ((sent + 127) & ~127)) return;
  }

  const ushort_t* B0 = B0g + (long)b * sB;
  const ushort_t* B1 = (BMODE == 1) ? B1g + (long)b * sB : nullptr;

  const int wid = tid >> 6, lane = tid & 63;
  const int wm = (wid >> 1) * 64, wn = (wid & 1) * 64;
  const int lr = lane & 15, lq = lane >> 4;

  floatx4 acc[4][4] = {};

  for (int k0 = 0; k0 < kend; k0 += BK) {
    // ---- stage A ----
    if constexpr (AMODE <= 1) {
      const float* A = (const float*)A0v + (long)b * sA;
#pragma unroll
      for (int j = 0; j < 4; ++j) {
        int idx = tid + j * 256;                   // 1024 float4 loads
        int r = idx >> 3, c = (idx & 7) * 4;
        float4 v = *(const float4*)(A + (row0 + r) * (long)K + k0 + c);
        ushort_t h0 = f2bf(v.x), h1 = f2bf(v.y), h2 = f2bf(v.z), h3 = f2bf(v.w);
        ushort_t* d = &As[0][r][c];
        d[0] = h0; d[1] = h1; d[2] = h2; d[3] = h3;
        if constexpr (AMODE == 1) {
          ushort_t* e = &As[1][r][c];
          e[0] = f2bf(v.x - bf2f(h0)); e[1] = f2bf(v.y - bf2f(h1));
          e[2] = f2bf(v.z - bf2f(h2)); e[3] = f2bf(v.w - bf2f(h3));
        }
      }
    } else {
      const ushort_t* A0 = (const ushort_t*)A0v + (long)b * sA;
      const ushort_t* A1 = (const ushort_t*)A1v + (long)b * sA;
#pragma unroll
      for (int j = 0; j < 2; ++j) {
        int idx = tid + j * 256;                   // 512 16B loads each
        int r = idx >> 2, c = (idx & 3) * 8;
        *(uint4*)&As[0][r][c] = *(const uint4*)(A0 + (row0 + r) * (long)K + k0 + c);
        *(uint4*)&As[1][r][c] = *(const uint4*)(A1 + (row0 + r) * (long)K + k0 + c);
      }
    }
    // ---- stage B ----
#pragma unroll
    for (int j = 0; j < 2; ++j) {
      int idx = tid + j * 256;
      int r = idx >> 2, c = (idx & 3) * 8;
      *(uint4*)&Bs[0][r][c] = *(const uint4*)(B0 + (col0 + r) * (long)K + k0 + c);
      if constexpr (BMODE == 1)
        *(uint4*)&Bs[1][r][c] = *(const uint4*)(B1 + (col0 + r) * (long)K + k0 + c);
    }
    __syncthreads();

    shortx8 ah[4], al[4], bh[4], bl[4];
#pragma unroll
    for (int t = 0; t < 4; ++t) {
      ah[t] = *(const shortx8*)&As[0][wm + t * 16 + lr][lq * 8];
      bh[t] = *(const shortx8*)&Bs[0][wn + t * 16 + lr][lq * 8];
      if constexpr (NA == 2) al[t] = *(const shortx8*)&As[1][wm + t * 16 + lr][lq * 8];
      if constexpr (NB == 2) bl[t] = *(const shortx8*)&Bs[1][wn + t * 16 + lr][lq * 8];
    }
#pragma unroll
    for (int mt = 0; mt < 4; ++mt)
#pragma unroll
      for (int nt = 0; nt < 4; ++nt) {
        acc[mt][nt] = __builtin_amdgcn_mfma_f32_16x16x32_bf16(ah[mt], bh[nt], acc[mt][nt], 0, 0, 0);
        if constexpr (DUAL) {
          acc[mt][nt] = __builtin_amdgcn_mfma_f32_16x16x32_bf16(ah[mt], bl[nt], acc[mt][nt], 0, 0, 0);
          acc[mt][nt] = __builtin_amdgcn_mfma_f32_16x16x32_bf16(al[mt], bh[nt], acc[mt][nt], 0, 0, 0);
        }
      }
    __syncthreads();
  }

  // C/D layout (verified m89/m91): col = lane&15, row = (lane>>4)*4 + reg
#pragma unroll
  for (int mt = 0; mt < 4; ++mt) {
#pragma unroll
    for (int nt = 0; nt < 4; ++nt) {
      long col = col0 + wn + nt * 16 + lr;
      if constexpr (OMODE == 2) {
        long row = row0 + wm + mt * 16 + lq * 4;   // 4 consecutive s per lane
        long bb = row >> 12, s = row & 4095;
        ushort4 pk;
        pk.x = f2bf(acc[mt][nt][0]); pk.y = f2bf(acc[mt][nt][1]);
        pk.z = f2bf(acc[mt][nt][2]); pk.w = f2bf(acc[mt][nt][3]);
        *(ushort4*)&((ushort_t*)C0v)[bb * bstride + col * ldc + s] = pk;
      } else {
#pragma unroll
        for (int r = 0; r < 4; ++r) {
          long row = row0 + wm + mt * 16 + lq * 4 + r;
          float v = acc[mt][nt][r];
          if constexpr (OMODE == 0) {
            (((float*)C0v) + (long)b * sC)[row * ldc + col] = v;
          } else {
            ushort_t h = f2bf(v);
            ((ushort_t*)C0v)[row * ldc + col] = h;
            ((ushort_t*)C1v)[row * ldc + col] = f2bf(v - bf2f(h));
          }
        }
      }
    }
  }
}

__global__ __launch_bounds__(256)
void cast_w_split(const float* __restrict__ in, ushort_t* __restrict__ hi,
                  ushort_t* __restrict__ lo, int n4) {
  int i = blockIdx.x * 256 + threadIdx.x;
  if (i < n4) {
    float4 v = ((const float4*)in)[i];
    ushort4 h, l;
    h.x = f2bf(v.x); l.x = f2bf(v.x - bf2f(h.x));
    h.y = f2bf(v.y); l.y = f2bf(v.y - bf2f(h.y));
    h.z = f2bf(v.z); l.z = f2bf(v.z - bf2f(h.z));
    h.w = f2bf(v.w); l.w = f2bf(v.w - bf2f(h.w));
    ((ushort4*)hi)[i] = h;
    ((ushort4*)lo)[i] = l;
  }
}

// In-place masked softmax; processes only c < roundup(sent,128) (rest unused).
__global__ __launch_bounds__(256)
void softmax_rows(float* __restrict__ scores, const int* __restrict__ length, int b0) {
  const long row = blockIdx.x;
  const int b = b0 + (int)(row >> 12);
  float* p = scores + row * 4096;
  const int sent = length[b] * 2;
  const int sentceil = (sent + 127) & ~127;
  const int tid = threadIdx.x;
  float vals[16];
  float mx = -3.4e38f;
  int nj = 0;
  for (int c = tid; c < sentceil; c += 256) {
    float v = p[c];
    v = (c < sent) ? v : -2147483648.0f;   // NEG_BIG
    vals[nj++] = v;
    mx = fmaxf(mx, v);
  }
#pragma unroll
  for (int off = 32; off > 0; off >>= 1) mx = fmaxf(mx, __shfl_down(mx, off));
  __shared__ float red[8];
  if ((tid & 63) == 0) red[tid >> 6] = mx;
  __syncthreads();
  mx = fmaxf(fmaxf(red[0], red[1]), fmaxf(red[2], red[3]));
  float sum = 0.f;
  for (int j = 0; j < nj; ++j) { vals[j] = __expf(vals[j] - mx); sum += vals[j]; }
#pragma unroll
  for (int off = 32; off > 0; off >>= 1) sum += __shfl_down(sum, off);
  __syncthreads();
  if ((tid & 63) == 0) red[tid >> 6] = sum;
  __syncthreads();
  float inv = 1.0f / (red[0] + red[1] + red[2] + red[3]);
  int j = 0;
  for (int c = tid; c < sentceil; c += 256) p[c] = vals[j++] * inv;
}

extern "C" void kernel_launch(void* const* d_in, const int* in_sizes, int n_in,
                              void* d_out, int out_size, void* d_ws, size_t ws_size,
                              hipStream_t stream) {
  const float* X   = (const float*)d_in[0];   // [4,4096,1024]
  const int*   len = (const int*)d_in[1];     // [4]
  const float* Wq  = (const float*)d_in[2];   // [1024,1024]
  const float* Wk  = (const float*)d_in[3];
  const float* Wv  = (const float*)d_in[4];
  float* out = (float*)d_out;

  const int Bn = 4, S = 4096, D = 1024;
  const long MS = (long)Bn * S;               // 16384

  char* w = (char*)d_ws;
  ushort_t* Qhi = (ushort_t*)w; w += MS * D * 2;
  ushort_t* Qlo = (ushort_t*)w; w += MS * D * 2;
  ushort_t* Khi = (ushort_t*)w; w += MS * D * 2;
  ushort_t* Klo = (ushort_t*)w; w += MS * D * 2;
  ushort_t* Vt  = (ushort_t*)w; w += MS * D * 2;        // bf16 [B][D][S]
  ushort_t* Wqh = (ushort_t*)w; w += (long)D * D * 2;
  ushort_t* Wql = (ushort_t*)w; w += (long)D * D * 2;
  ushort_t* Wkh = (ushort_t*)w; w += (long)D * D * 2;
  ushort_t* Wkl = (ushort_t*)w; w += (long)D * D * 2;
  ushort_t* Wvh = (ushort_t*)w; w += (long)D * D * 2;
  ushort_t* Wvl = (ushort_t*)w; w += (long)D * D * 2;
  float*    sc  = (float*)w;                            // fp32 scores
  const size_t used_base = (size_t)(w - (char*)d_ws);
  const bool batched = ws_size >= used_base + 4ul * S * S * 4ul;

  const int n4 = D * D / 4;
  cast_w_split<<<(n4 + 255) / 256, 256, 0, stream>>>(Wq, Wqh, Wql, n4);
  cast_w_split<<<(n4 + 255) / 256, 256, 0, stream>>>(Wk, Wkh, Wkl, n4);
  cast_w_split<<<(n4 + 255) / 256, 256, 0, stream>>>(Wv, Wvh, Wvl, n4);

  dim3 blk(256);
  dim3 gproj(MS / BM, D / BN);                // (128, 8)
  // Q proj: all rows needed (queries are unmasked)
  gemm_bt<1, 1, 1, 0><<<gproj, blk, 0, stream>>>(X, nullptr, Wqh, Wql, Qhi, Qlo,
                                                 D, D, 0, len, 0, 0, 0, 0);
  // K proj: rows >= roundup(sent,128) are never read -> skip
  gemm_bt<1, 1, 1, 3><<<gproj, blk, 0, stream>>>(X, nullptr, Wkh, Wkl, Khi, Klo,
                                                 D, D, 0, len, 0, 0, 0, 0);
  // V proj: single bf16, transposed per batch, same row skip
  gemm_bt<0, 0, 2, 3><<<gproj, blk, 0, stream>>>(X, nullptr, Wvh, nullptr, Vt, nullptr,
                                                 D, S, (long)D * S, len, 0, 0, 0, 0);

  if (batched) {
    gemm_bt<2, 1, 0, 1><<<dim3(S / BM, S / BN, Bn), blk, 0, stream>>>(
        Qhi, Qlo, Khi, Klo, sc, nullptr, D, S, 0, len, 0,
        (long)S * D, (long)S * D, (long)S * S);
    softmax_rows<<<MS, 256, 0, stream>>>(sc, len, 0);
    gemm_bt<0, 0, 0, 2><<<dim3(S / BM, D / BN, Bn), blk, 0, stream>>>(
        sc, nullptr, Vt, nullptr, out, nullptr, S, D, 0, len, 0,
        (long)S * S, (long)D * S, (long)S * D);
  } else {
    for (int b = 0; b < Bn; ++b) {
      const long so = (long)b * S * D;
      gemm_bt<2, 1, 0, 1><<<dim3(S / BM, S / BN, 1), blk, 0, stream>>>(
          Qhi + so, Qlo + so, Khi + so, Klo + so, sc, nullptr, D, S, 0,
          len, b, 0, 0, 0);
      softmax_rows<<<S, 256, 0, stream>>>(sc, len, b);
      gemm_bt<0, 0, 0, 2><<<dim3(S / BM, D / BN, 1), blk, 0, stream>>>(
          sc, nullptr, Vt + (long)b * D * S, nullptr, out + so, nullptr, S, D, 0,
          len, b, 0, 0, 0);
    }
  }
}

// Round 5
// 911.726 us; speedup vs baseline: 1.6127x; 1.1270x over previous
//
#include <hip/hip_runtime.h>

// ---------------------------------------------------------------------------
// Self-attention (B=4, S=4096, D=1024), fp32 in/out.
// Precision: dual-bf16 (hi+lo split, 3-term MFMA) on the Q/K chain — logits
// are unscaled (sigma~32, near-argmax softmax). V / PV single-bf16.
// R5: R4's global_load_lds staging, but sc ALIASES the Xhi/Xlo region
// (dead after projections) so the non-batched footprint is 236 MB — R3's
// proven-working size. R4 crashed because sc at offset 236 MB overflowed
// ws (<300 MB; R3's dispatch pattern shows non-batched ran -> ws < 428 MB).
// ---------------------------------------------------------------------------

#define BM 128
#define BN 128
#define BK 32

typedef __attribute__((ext_vector_type(4))) float floatx4;
typedef __attribute__((ext_vector_type(8))) short shortx8;
typedef unsigned short ushort_t;

__device__ __forceinline__ ushort_t f2bf(float f) {
  union { float f; unsigned u; } x; x.f = f;
  unsigned r = x.u + 0x7fffu + ((x.u >> 16) & 1u);  // RNE
  return (ushort_t)(r >> 16);
}
__device__ __forceinline__ float bf2f(ushort_t h) {
  union { unsigned u; float f; } x; x.u = ((unsigned)h) << 16; return x.f;
}

// Async global->LDS, 16B per lane (m97 lever). LDS dest is wave-uniform base
// + lane*16 (m104/m108); our lane->LDS mapping is contiguous in lane order.
// Generic LDS pointer low 32 bits = LDS offset (aperture is 2^32-aligned).
__device__ __forceinline__ void gload_lds16(const ushort_t* g, ushort_t* l) {
  __builtin_amdgcn_global_load_lds(
      (__attribute__((address_space(1))) void*)(uintptr_t)g,
      (__attribute__((address_space(3))) void*)(unsigned)(uintptr_t)l,
      16, 0, 0);
}

// C = A * B^T.  A: NA bf16 streams [M,K] stride lda; B: NB bf16 streams
// [N,K] stride K. DUAL (NA==NB==2): 3-term hi/lo MFMA.
// OMODE: 0 = C fp32 [row*ldc+col] (+b*sC); 1 = C bf16 pair [row*ldc+col];
//        2 = C bf16 single, per-batch transposed [b*bstride+col*ldc+(row&4095)]
// LMODE: 0 none; 1 skip block if col0>=sent (QK^T); 2 kend=roundup(sent,128)
//        (PV); 3 skip block if (row0&4095)>=roundup(sent,128) (K/V proj)
template<int NA, int NB, int OMODE, int LMODE>
__global__ __launch_bounds__(256)
void gemm_bt(const ushort_t* __restrict__ A0g, const ushort_t* __restrict__ A1g,
             const ushort_t* __restrict__ B0g, const ushort_t* __restrict__ B1g,
             void* __restrict__ C0v, void* __restrict__ C1v,
             int K, int lda, int ldc, long bstride,
             const int* __restrict__ lenp, int b0, long sA, long sB, long sC)
{
  constexpr bool DUAL = (NA == 2) && (NB == 2);
  __shared__ ushort_t As[NA][BM][BK];
  __shared__ ushort_t Bs[NB][BN][BK];

  const int tid = threadIdx.x;
  const long row0 = (long)blockIdx.x * BM;
  const long col0 = (long)blockIdx.y * BN;
  const int b = b0 + blockIdx.z;

  int kend = K;
  if constexpr (LMODE == 1 || LMODE == 2) {
    const int sent = lenp[b] * 2;
    if constexpr (LMODE == 1) { if (col0 >= sent) return; }
    else kend = (sent + 127) & ~127;
  } else if constexpr (LMODE == 3) {
    const int sent = lenp[row0 >> 12] * 2;
    if ((int)(row0 & 4095) >= ((sent + 127) & ~127)) return;
  }

  // staging: idx = tid + j*256; row = idx>>2, col = (idx&3)*8; LDS flat = idx*16B
  const int sr = tid >> 2, scol = (tid & 3) * 8;
  const ushort_t* pA0 = A0g + (long)b * sA + (row0 + sr) * (long)lda + scol;
  const ushort_t* pA1 = (NA == 2) ? A1g + (long)b * sA + (row0 + sr) * (long)lda + scol : nullptr;
  const ushort_t* pB0 = B0g + (long)b * sB + (col0 + sr) * (long)K + scol;
  const ushort_t* pB1 = (NB == 2) ? B1g + (long)b * sB + (col0 + sr) * (long)K + scol : nullptr;
  ushort_t* lA0 = &As[0][sr][scol];
  ushort_t* lA1 = (NA == 2) ? &As[NA - 1][sr][scol] : nullptr;
  ushort_t* lB0 = &Bs[0][sr][scol];
  ushort_t* lB1 = (NB == 2) ? &Bs[NB - 1][sr][scol] : nullptr;
  const long jA = 64 * (long)lda, jB = 64 * (long)K;  // +64 rows per j

  const int wid = tid >> 6, lane = tid & 63;
  const int wm = (wid >> 1) * 64, wn = (wid & 1) * 64;
  const int lr = lane & 15, lq = lane >> 4;

  floatx4 acc[4][4] = {};

  for (int k0 = 0; k0 < kend; k0 += BK) {
#pragma unroll
    for (int j = 0; j < 2; ++j) {
      gload_lds16(pA0 + k0 + j * jA, lA0 + j * 2048);
      if constexpr (NA == 2) gload_lds16(pA1 + k0 + j * jA, lA1 + j * 2048);
      gload_lds16(pB0 + k0 + j * jB, lB0 + j * 2048);
      if constexpr (NB == 2) gload_lds16(pB1 + k0 + j * jB, lB1 + j * 2048);
    }
    __syncthreads();

    shortx8 ah[4], al[4], bh[4], bl[4];
#pragma unroll
    for (int t = 0; t < 4; ++t) {
      ah[t] = *(const shortx8*)&As[0][wm + t * 16 + lr][lq * 8];
      bh[t] = *(const shortx8*)&Bs[0][wn + t * 16 + lr][lq * 8];
      if constexpr (NA == 2) al[t] = *(const shortx8*)&As[1][wm + t * 16 + lr][lq * 8];
      if constexpr (NB == 2) bl[t] = *(const shortx8*)&Bs[1][wn + t * 16 + lr][lq * 8];
    }
#pragma unroll
    for (int mt = 0; mt < 4; ++mt)
#pragma unroll
      for (int nt = 0; nt < 4; ++nt) {
        acc[mt][nt] = __builtin_amdgcn_mfma_f32_16x16x32_bf16(ah[mt], bh[nt], acc[mt][nt], 0, 0, 0);
        if constexpr (DUAL) {
          acc[mt][nt] = __builtin_amdgcn_mfma_f32_16x16x32_bf16(ah[mt], bl[nt], acc[mt][nt], 0, 0, 0);
          acc[mt][nt] = __builtin_amdgcn_mfma_f32_16x16x32_bf16(al[mt], bh[nt], acc[mt][nt], 0, 0, 0);
        }
      }
    __syncthreads();
  }

  // C/D layout (verified m89/m91): col = lane&15, row = (lane>>4)*4 + reg
#pragma unroll
  for (int mt = 0; mt < 4; ++mt) {
#pragma unroll
    for (int nt = 0; nt < 4; ++nt) {
      long col = col0 + wn + nt * 16 + lr;
      if constexpr (OMODE == 2) {
        long row = row0 + wm + mt * 16 + lq * 4;   // 4 consecutive s per lane
        long bb = row >> 12, s = row & 4095;
        ushort4 pk;
        pk.x = f2bf(acc[mt][nt][0]); pk.y = f2bf(acc[mt][nt][1]);
        pk.z = f2bf(acc[mt][nt][2]); pk.w = f2bf(acc[mt][nt][3]);
        *(ushort4*)&((ushort_t*)C0v)[bb * bstride + col * ldc + s] = pk;
      } else {
#pragma unroll
        for (int r = 0; r < 4; ++r) {
          long row = row0 + wm + mt * 16 + lq * 4 + r;
          float v = acc[mt][nt][r];
          if constexpr (OMODE == 0) {
            (((float*)C0v) + (long)b * sC)[row * ldc + col] = v;
          } else {
            ushort_t h = f2bf(v);
            ((ushort_t*)C0v)[row * ldc + col] = h;
            ((ushort_t*)C1v)[row * ldc + col] = f2bf(v - bf2f(h));
          }
        }
      }
    }
  }
}

__global__ __launch_bounds__(256)
void cast_split(const float* __restrict__ in, ushort_t* __restrict__ hi,
                ushort_t* __restrict__ lo, int n4) {
  int i = blockIdx.x * 256 + threadIdx.x;
  if (i < n4) {
    float4 v = ((const float4*)in)[i];
    ushort4 h, l;
    h.x = f2bf(v.x); l.x = f2bf(v.x - bf2f(h.x));
    h.y = f2bf(v.y); l.y = f2bf(v.y - bf2f(h.y));
    h.z = f2bf(v.z); l.z = f2bf(v.z - bf2f(h.z));
    h.w = f2bf(v.w); l.w = f2bf(v.w - bf2f(h.w));
    ((ushort4*)hi)[i] = h;
    ((ushort4*)lo)[i] = l;
  }
}

// Masked softmax over one score row; reads fp32, writes bf16 P into the first
// half of the same row's storage (all reads precede writes: reduction
// barriers order them; only c < roundup(sent,128) is consumed downstream).
__global__ __launch_bounds__(256)
void softmax_rows(float* __restrict__ scores, const int* __restrict__ length, int b0) {
  const long row = blockIdx.x;
  const int b = b0 + (int)(row >> 12);
  float* p = scores + row * 4096;
  const int sent = length[b] * 2;
  const int sentceil = (sent + 127) & ~127;
  const int tid = threadIdx.x;
  float vals[16];
  float mx = -3.4e38f;
  int nj = 0;
  for (int c = tid; c < sentceil; c += 256) {
    float v = p[c];
    v = (c < sent) ? v : -2147483648.0f;   // NEG_BIG
    vals[nj++] = v;
    mx = fmaxf(mx, v);
  }
#pragma unroll
  for (int off = 32; off > 0; off >>= 1) mx = fmaxf(mx, __shfl_down(mx, off));
  __shared__ float red[8];
  if ((tid & 63) == 0) red[tid >> 6] = mx;
  __syncthreads();
  mx = fmaxf(fmaxf(red[0], red[1]), fmaxf(red[2], red[3]));
  float sum = 0.f;
  for (int j = 0; j < nj; ++j) { vals[j] = __expf(vals[j] - mx); sum += vals[j]; }
#pragma unroll
  for (int off = 32; off > 0; off >>= 1) sum += __shfl_down(sum, off);
  __syncthreads();
  if ((tid & 63) == 0) red[tid >> 6] = sum;
  __syncthreads();
  float inv = 1.0f / (red[0] + red[1] + red[2] + red[3]);
  ushort_t* pb = (ushort_t*)p;           // bf16 row, stride 8192 ushorts
  int j = 0;
  for (int c = tid; c < sentceil; c += 256) pb[c] = f2bf(vals[j++] * inv);
}

extern "C" void kernel_launch(void* const* d_in, const int* in_sizes, int n_in,
                              void* d_out, int out_size, void* d_ws, size_t ws_size,
                              hipStream_t stream) {
  const float* X   = (const float*)d_in[0];   // [4,4096,1024]
  const int*   len = (const int*)d_in[1];     // [4]
  const float* Wq  = (const float*)d_in[2];   // [1024,1024]
  const float* Wk  = (const float*)d_in[3];
  const float* Wv  = (const float*)d_in[4];
  float* out = (float*)d_out;

  const int Bn = 4, S = 4096, D = 1024;
  const long MS = (long)Bn * S;               // 16384

  char* w = (char*)d_ws;
  ushort_t* Xhi = (ushort_t*)w; w += MS * D * 2;        // dead after projections
  ushort_t* Xlo = (ushort_t*)w; w += MS * D * 2;        // dead after projections
  ushort_t* Qhi = (ushort_t*)w; w += MS * D * 2;
  ushort_t* Qlo = (ushort_t*)w; w += MS * D * 2;
  ushort_t* Khi = (ushort_t*)w; w += MS * D * 2;
  ushort_t* Klo = (ushort_t*)w; w += MS * D * 2;
  ushort_t* Vt  = (ushort_t*)w; w += MS * D * 2;        // bf16 [B][D][S]
  ushort_t* Wqh = (ushort_t*)w; w += (long)D * D * 2;
  ushort_t* Wql = (ushort_t*)w; w += (long)D * D * 2;
  ushort_t* Wkh = (ushort_t*)w; w += (long)D * D * 2;
  ushort_t* Wkl = (ushort_t*)w; w += (long)D * D * 2;
  ushort_t* Wvh = (ushort_t*)w; w += (long)D * D * 2;
  ushort_t* Wvl = (ushort_t*)w; w += (long)D * D * 2;
  const size_t used_base = (size_t)(w - (char*)d_ws);   // 236 MB
  // Batched scores need 256 MB AFTER everything (Q/K live during QK^T).
  const bool batched = ws_size >= used_base + 4ul * S * S * 4ul;
  // Non-batched scores (64 MB) alias Xhi/Xlo — dead once projections finish.
  float* sc = batched ? (float*)w : (float*)d_ws;

  const int n4w = D * D / 4;
  cast_split<<<(int)(MS * D / 4 + 255) / 256, 256, 0, stream>>>(X, Xhi, Xlo, (int)(MS * D / 4));
  cast_split<<<(n4w + 255) / 256, 256, 0, stream>>>(Wq, Wqh, Wql, n4w);
  cast_split<<<(n4w + 255) / 256, 256, 0, stream>>>(Wk, Wkh, Wkl, n4w);
  cast_split<<<(n4w + 255) / 256, 256, 0, stream>>>(Wv, Wvh, Wvl, n4w);

  dim3 blk(256);
  dim3 gproj(MS / BM, D / BN);                // (128, 8)
  // Q proj: all rows (queries unmasked), dual in/out
  gemm_bt<2, 2, 1, 0><<<gproj, blk, 0, stream>>>(Xhi, Xlo, Wqh, Wql, Qhi, Qlo,
                                                 D, D, D, 0, len, 0, 0, 0, 0);
  // K proj: rows >= roundup(sent,128) never read -> skip
  gemm_bt<2, 2, 1, 3><<<gproj, blk, 0, stream>>>(Xhi, Xlo, Wkh, Wkl, Khi, Klo,
                                                 D, D, D, 0, len, 0, 0, 0, 0);
  // V proj: single bf16, transposed per batch, same row skip
  gemm_bt<1, 1, 2, 3><<<gproj, blk, 0, stream>>>(Xhi, nullptr, Wvh, nullptr, Vt, nullptr,
                                                 D, D, S, (long)D * S, len, 0, 0, 0, 0);

  if (batched) {
    gemm_bt<2, 2, 0, 1><<<dim3(S / BM, S / BN, Bn), blk, 0, stream>>>(
        Qhi, Qlo, Khi, Klo, sc, nullptr, D, D, S, 0, len, 0,
        (long)S * D, (long)S * D, (long)S * S);
    softmax_rows<<<(int)MS, 256, 0, stream>>>(sc, len, 0);
    gemm_bt<1, 1, 0, 2><<<dim3(S / BM, D / BN, Bn), blk, 0, stream>>>(
        (const ushort_t*)sc, nullptr, Vt, nullptr, out, nullptr, S, 2 * S, D, 0,
        len, 0, (long)S * 2 * S, (long)D * S, (long)S * D);
  } else {
    for (int b = 0; b < Bn; ++b) {
      const long so = (long)b * S * D;
      gemm_bt<2, 2, 0, 1><<<dim3(S / BM, S / BN, 1), blk, 0, stream>>>(
          Qhi + so, Qlo + so, Khi + so, Klo + so, sc, nullptr, D, D, S, 0,
          len, b, 0, 0, 0);
      softmax_rows<<<S, 256, 0, stream>>>(sc, len, b);
      gemm_bt<1, 1, 0, 2><<<dim3(S / BM, D / BN, 1), blk, 0, stream>>>(
          (const ushort_t*)sc, nullptr, Vt + (long)b * D * S, nullptr, out + so, nullptr,
          S, 2 * S, D, 0, len, b, 0, 0, 0);
    }
  }
}

// Round 6
// 860.360 us; speedup vs baseline: 1.7090x; 1.0597x over previous
//
#include <hip/hip_runtime.h>

// ---------------------------------------------------------------------------
// Self-attention (B=4, S=4096, D=1024), fp32 in/out.
// Precision: dual-bf16 (hi+lo split, 3-term MFMA) on the Q/K chain — logits
// are unscaled (sigma~32, near-argmax softmax). V / PV single-bf16.
// R6: PV uses a 128x64 tile (512 blocks = 2/CU vs 1/CU: PV was latency-capped
// at ~400 TF with 4 waves/CU); Q+K projections merged into one z=2 dispatch
// (shared X operand, z-strided weights/outputs); weight casts merged.
// QK^T itself sits at the m97 structural plateau (~873 TF) — left alone.
// ws: [Xhi|Xlo](=sc after projections)|Qhi|Qlo|Khi|Klo|Vt|W... ~248 MB.
// ---------------------------------------------------------------------------

typedef __attribute__((ext_vector_type(4))) float floatx4;
typedef __attribute__((ext_vector_type(8))) short shortx8;
typedef unsigned short ushort_t;

__device__ __forceinline__ ushort_t f2bf(float f) {
  union { float f; unsigned u; } x; x.f = f;
  unsigned r = x.u + 0x7fffu + ((x.u >> 16) & 1u);  // RNE
  return (ushort_t)(r >> 16);
}
__device__ __forceinline__ float bf2f(ushort_t h) {
  union { unsigned u; float f; } x; x.u = ((unsigned)h) << 16; return x.f;
}

// Async global->LDS, 16B per lane (m97 lever). LDS dest = wave-uniform base
// + lane*16 (m104/m108); our lane->LDS mapping is contiguous in lane order.
__device__ __forceinline__ void gload_lds16(const ushort_t* g, ushort_t* l) {
  __builtin_amdgcn_global_load_lds(
      (__attribute__((address_space(1))) void*)(uintptr_t)g,
      (__attribute__((address_space(3))) void*)(unsigned)(uintptr_t)l,
      16, 0, 0);
}

// C = A * B^T. Tile BM=TM*32 x BN=TN*32, 256 threads = 4 waves in 2x2.
// A: NA bf16 streams [M,K] stride lda (z-stride sA); B: NB bf16 streams
// [N,K] stride K (z-stride sB). DUAL (NA==NB==2): 3-term hi/lo MFMA.
// OMODE: 0 = C fp32 [z*sC + row*ldc+col]; 1 = C bf16 pair [z*sC + row*ldc+col];
//        2 = C bf16 single, per-batch transposed [(row>>12)*bstride+col*ldc+(row&4095)]
// LMODE: 0 none; 1 skip block if col0>=sent(b0+z) (QK^T);
//        2 kend=roundup(sent(b0+z),128) (PV);
//        3 skip block if (row0&4095)>=roundup(sent(row0>>12),128) (V proj);
//        4 like 3 but only for z==1 (merged Q+K proj: z=0 Q full, z=1 K skip)
template<int TM, int TN, int NA, int NB, int OMODE, int LMODE>
__global__ __launch_bounds__(256)
void gemm_bt(const ushort_t* __restrict__ A0g, const ushort_t* __restrict__ A1g,
             const ushort_t* __restrict__ B0g, const ushort_t* __restrict__ B1g,
             void* __restrict__ C0v, void* __restrict__ C1v,
             int K, int lda, int ldc, long bstride,
             const int* __restrict__ lenp, int b0, long sA, long sB, long sC)
{
  constexpr int BM = TM * 32, BN = TN * 32;
  constexpr int LA = TM / 2, LB = TN / 2;   // 16B-loads per thread per stream
  constexpr bool DUAL = (NA == 2) && (NB == 2);
  __shared__ ushort_t As[NA][BM][32];
  __shared__ ushort_t Bs[NB][BN][32];

  const int tid = threadIdx.x;
  const int z = blockIdx.z;
  const long row0 = (long)blockIdx.x * BM;
  const long col0 = (long)blockIdx.y * BN;

  int kend = K;
  if constexpr (LMODE == 1 || LMODE == 2) {
    const int sent = lenp[b0 + z] * 2;
    if constexpr (LMODE == 1) { if (col0 >= sent) return; }
    else kend = (sent + 127) & ~127;
  } else if constexpr (LMODE == 3) {
    const int sent = lenp[row0 >> 12] * 2;
    if ((int)(row0 & 4095) >= ((sent + 127) & ~127)) return;
  } else if constexpr (LMODE == 4) {
    if (z == 1) {
      const int sent = lenp[row0 >> 12] * 2;
      if ((int)(row0 & 4095) >= ((sent + 127) & ~127)) return;
    }
  }

  // staging: idx = tid + j*256; row = idx>>2, col = (idx&3)*8; LDS flat = idx*16B
  const int sr = tid >> 2, scol = (tid & 3) * 8;
  const ushort_t* pA0 = A0g + z * sA + (row0 + sr) * (long)lda + scol;
  const ushort_t* pA1 = (NA == 2) ? A1g + z * sA + (row0 + sr) * (long)lda + scol : nullptr;
  const ushort_t* pB0 = B0g + z * sB + (col0 + sr) * (long)K + scol;
  const ushort_t* pB1 = (NB == 2) ? B1g + z * sB + (col0 + sr) * (long)K + scol : nullptr;
  ushort_t* lA0 = &As[0][sr][scol];
  ushort_t* lA1 = (NA == 2) ? &As[NA - 1][sr][scol] : nullptr;
  ushort_t* lB0 = &Bs[0][sr][scol];
  ushort_t* lB1 = (NB == 2) ? &Bs[NB - 1][sr][scol] : nullptr;
  const long jA = 64 * (long)lda, jB = 64 * (long)K;  // +64 rows per j

  const int wid = tid >> 6, lane = tid & 63;
  const int wm = (wid >> 1) * (BM / 2), wn = (wid & 1) * (BN / 2);
  const int lr = lane & 15, lq = lane >> 4;

  floatx4 acc[TM][TN] = {};

  for (int k0 = 0; k0 < kend; k0 += 32) {
#pragma unroll
    for (int j = 0; j < LA; ++j) {
      gload_lds16(pA0 + k0 + j * jA, lA0 + j * 2048);
      if constexpr (NA == 2) gload_lds16(pA1 + k0 + j * jA, lA1 + j * 2048);
    }
#pragma unroll
    for (int j = 0; j < LB; ++j) {
      gload_lds16(pB0 + k0 + j * jB, lB0 + j * 2048);
      if constexpr (NB == 2) gload_lds16(pB1 + k0 + j * jB, lB1 + j * 2048);
    }
    __syncthreads();

    shortx8 ah[TM], al[TM], bh[TN], bl[TN];
#pragma unroll
    for (int t = 0; t < TM; ++t) {
      ah[t] = *(const shortx8*)&As[0][wm + t * 16 + lr][lq * 8];
      if constexpr (NA == 2) al[t] = *(const shortx8*)&As[1][wm + t * 16 + lr][lq * 8];
    }
#pragma unroll
    for (int t = 0; t < TN; ++t) {
      bh[t] = *(const shortx8*)&Bs[0][wn + t * 16 + lr][lq * 8];
      if constexpr (NB == 2) bl[t] = *(const shortx8*)&Bs[1][wn + t * 16 + lr][lq * 8];
    }
#pragma unroll
    for (int mt = 0; mt < TM; ++mt)
#pragma unroll
      for (int nt = 0; nt < TN; ++nt) {
        acc[mt][nt] = __builtin_amdgcn_mfma_f32_16x16x32_bf16(ah[mt], bh[nt], acc[mt][nt], 0, 0, 0);
        if constexpr (DUAL) {
          acc[mt][nt] = __builtin_amdgcn_mfma_f32_16x16x32_bf16(ah[mt], bl[nt], acc[mt][nt], 0, 0, 0);
          acc[mt][nt] = __builtin_amdgcn_mfma_f32_16x16x32_bf16(al[mt], bh[nt], acc[mt][nt], 0, 0, 0);
        }
      }
    __syncthreads();
  }

  // C/D layout (verified m89/m91): col = lane&15, row = (lane>>4)*4 + reg
#pragma unroll
  for (int mt = 0; mt < TM; ++mt) {
#pragma unroll
    for (int nt = 0; nt < TN; ++nt) {
      long col = col0 + wn + nt * 16 + lr;
      if constexpr (OMODE == 2) {
        long row = row0 + wm + mt * 16 + lq * 4;   // 4 consecutive s per lane
        long bb = row >> 12, s = row & 4095;
        ushort4 pk;
        pk.x = f2bf(acc[mt][nt][0]); pk.y = f2bf(acc[mt][nt][1]);
        pk.z = f2bf(acc[mt][nt][2]); pk.w = f2bf(acc[mt][nt][3]);
        *(ushort4*)&((ushort_t*)C0v)[bb * bstride + col * ldc + s] = pk;
      } else {
#pragma unroll
        for (int r = 0; r < 4; ++r) {
          long row = row0 + wm + mt * 16 + lq * 4 + r;
          float v = acc[mt][nt][r];
          if constexpr (OMODE == 0) {
            ((float*)C0v)[z * sC + row * ldc + col] = v;
          } else {
            ushort_t h = f2bf(v);
            ((ushort_t*)C0v)[z * sC + row * ldc + col] = h;
            ((ushort_t*)C1v)[z * sC + row * ldc + col] = f2bf(v - bf2f(h));
          }
        }
      }
    }
  }
}

__global__ __launch_bounds__(256)
void cast_split(const float* __restrict__ in, ushort_t* __restrict__ hi,
                ushort_t* __restrict__ lo, int n4) {
  int i = blockIdx.x * 256 + threadIdx.x;
  if (i < n4) {
    float4 v = ((const float4*)in)[i];
    ushort4 h, l;
    h.x = f2bf(v.x); l.x = f2bf(v.x - bf2f(h.x));
    h.y = f2bf(v.y); l.y = f2bf(v.y - bf2f(h.y));
    h.z = f2bf(v.z); l.z = f2bf(v.z - bf2f(h.z));
    h.w = f2bf(v.w); l.w = f2bf(v.w - bf2f(h.w));
    ((ushort4*)hi)[i] = h;
    ((ushort4*)lo)[i] = l;
  }
}

// 3 weight splits in one dispatch (blockIdx.y selects the matrix).
__global__ __launch_bounds__(256)
void cast_w3(const float* __restrict__ w0, const float* __restrict__ w1,
             const float* __restrict__ w2, ushort_t* __restrict__ h0,
             ushort_t* __restrict__ l0, ushort_t* __restrict__ h1,
             ushort_t* __restrict__ l1, ushort_t* __restrict__ h2,
             ushort_t* __restrict__ l2, int n4) {
  int i = blockIdx.x * 256 + threadIdx.x;
  if (i >= n4) return;
  const float* in = (blockIdx.y == 0) ? w0 : (blockIdx.y == 1) ? w1 : w2;
  ushort_t* hi = (blockIdx.y == 0) ? h0 : (blockIdx.y == 1) ? h1 : h2;
  ushort_t* lo = (blockIdx.y == 0) ? l0 : (blockIdx.y == 1) ? l1 : l2;
  float4 v = ((const float4*)in)[i];
  ushort4 h, l;
  h.x = f2bf(v.x); l.x = f2bf(v.x - bf2f(h.x));
  h.y = f2bf(v.y); l.y = f2bf(v.y - bf2f(h.y));
  h.z = f2bf(v.z); l.z = f2bf(v.z - bf2f(h.z));
  h.w = f2bf(v.w); l.w = f2bf(v.w - bf2f(h.w));
  ((ushort4*)hi)[i] = h;
  ((ushort4*)lo)[i] = l;
}

// Masked softmax over one score row; reads fp32, writes bf16 P into the first
// half of the same row's storage (reduction barriers order reads before
// writes; only c < roundup(sent,128) is consumed downstream).
__global__ __launch_bounds__(256)
void softmax_rows(float* __restrict__ scores, const int* __restrict__ length, int b0) {
  const long row = blockIdx.x;
  const int b = b0 + (int)(row >> 12);
  float* p = scores + row * 4096;
  const int sent = length[b] * 2;
  const int sentceil = (sent + 127) & ~127;
  const int tid = threadIdx.x;
  float vals[16];
  float mx = -3.4e38f;
  int nj = 0;
  for (int c = tid; c < sentceil; c += 256) {
    float v = p[c];
    v = (c < sent) ? v : -2147483648.0f;   // NEG_BIG
    vals[nj++] = v;
    mx = fmaxf(mx, v);
  }
#pragma unroll
  for (int off = 32; off > 0; off >>= 1) mx = fmaxf(mx, __shfl_down(mx, off));
  __shared__ float red[8];
  if ((tid & 63) == 0) red[tid >> 6] = mx;
  __syncthreads();
  mx = fmaxf(fmaxf(red[0], red[1]), fmaxf(red[2], red[3]));
  float sum = 0.f;
  for (int j = 0; j < nj; ++j) { vals[j] = __expf(vals[j] - mx); sum += vals[j]; }
#pragma unroll
  for (int off = 32; off > 0; off >>= 1) sum += __shfl_down(sum, off);
  __syncthreads();
  if ((tid & 63) == 0) red[tid >> 6] = sum;
  __syncthreads();
  float inv = 1.0f / (red[0] + red[1] + red[2] + red[3]);
  ushort_t* pb = (ushort_t*)p;           // bf16 row, stride 8192 ushorts
  int j = 0;
  for (int c = tid; c < sentceil; c += 256) pb[c] = f2bf(vals[j++] * inv);
}

extern "C" void kernel_launch(void* const* d_in, const int* in_sizes, int n_in,
                              void* d_out, int out_size, void* d_ws, size_t ws_size,
                              hipStream_t stream) {
  const float* X   = (const float*)d_in[0];   // [4,4096,1024]
  const int*   len = (const int*)d_in[1];     // [4]
  const float* Wq  = (const float*)d_in[2];   // [1024,1024]
  const float* Wk  = (const float*)d_in[3];
  const float* Wv  = (const float*)d_in[4];
  float* out = (float*)d_out;

  const int Bn = 4, S = 4096, D = 1024;
  const long MS = (long)Bn * S;               // 16384

  char* w = (char*)d_ws;
  ushort_t* Xhi = (ushort_t*)w; w += MS * D * 2;   // dead after projections
  ushort_t* Xlo = (ushort_t*)w; w += MS * D * 2;   // dead after projections
  // Q/K interleaved so the merged proj can z-stride: [Qhi][Qlo][Khi][Klo]
  ushort_t* Qhi = (ushort_t*)w; w += MS * D * 2;
  ushort_t* Qlo = (ushort_t*)w; w += MS * D * 2;
  ushort_t* Khi = (ushort_t*)w; w += MS * D * 2;
  ushort_t* Klo = (ushort_t*)w; w += MS * D * 2;
  ushort_t* Vt  = (ushort_t*)w; w += MS * D * 2;   // bf16 [B][D][S]
  // weights interleaved: [Wqh][Wql][Wkh][Wkl] for z-stride, then V
  ushort_t* Wqh = (ushort_t*)w; w += (long)D * D * 2;
  ushort_t* Wql = (ushort_t*)w; w += (long)D * D * 2;
  ushort_t* Wkh = (ushort_t*)w; w += (long)D * D * 2;
  ushort_t* Wkl = (ushort_t*)w; w += (long)D * D * 2;
  ushort_t* Wvh = (ushort_t*)w; w += (long)D * D * 2;
  ushort_t* Wvl = (ushort_t*)w; w += (long)D * D * 2;
  // scores (64 MB fp32) alias Xhi/Xlo — dead once projections finish.
  float* sc = (float*)d_ws;

  const int n4w = D * D / 4;
  cast_split<<<(int)(MS * D / 4 + 255) / 256, 256, 0, stream>>>(X, Xhi, Xlo, (int)(MS * D / 4));
  cast_w3<<<dim3((n4w + 255) / 256, 3), 256, 0, stream>>>(
      Wq, Wk, Wv, Wqh, Wql, Wkh, Wkl, Wvh, Wvl, n4w);

  dim3 blk(256);
  // Merged Q+K projections: z=0 -> Q (full), z=1 -> K (row-skip). A = X for
  // both z (sA=0); B z-stride 2*D*D (Wqh->Wkh, Wql->Wkl); C z-stride 2*MS*D.
  gemm_bt<4, 4, 2, 2, 1, 4><<<dim3(MS / 128, D / 128, 2), blk, 0, stream>>>(
      Xhi, Xlo, Wqh, Wql, Qhi, Qlo, D, D, D, 0, len, 0,
      0, 2 * (long)D * D, 2 * MS * D);
  // V proj: single bf16, transposed per batch, row-skip
  gemm_bt<4, 4, 1, 1, 2, 3><<<dim3(MS / 128, D / 128, 1), blk, 0, stream>>>(
      Xhi, nullptr, Wvh, nullptr, Vt, nullptr, D, D, S, (long)D * S,
      len, 0, 0, 0, 0);

  for (int b = 0; b < Bn; ++b) {
    const long so = (long)b * S * D;
    // QK^T dual (3-term), fp32 scores, col-block skip past sent
    gemm_bt<4, 4, 2, 2, 0, 1><<<dim3(S / 128, S / 128, 1), blk, 0, stream>>>(
        Qhi + so, Qlo + so, Khi + so, Klo + so, sc, nullptr, D, D, S, 0,
        len, b, 0, 0, 0);
    softmax_rows<<<S, 256, 0, stream>>>(sc, len, b);
    // PV: P bf16 (in-place rows, stride 2S), Vt single; 128x64 tile ->
    // 512 blocks = 2/CU (PV was latency-capped at 1 block/CU)
    gemm_bt<4, 2, 1, 1, 0, 2><<<dim3(S / 128, D / 64, 1), blk, 0, stream>>>(
        (const ushort_t*)sc, nullptr, Vt + (long)b * D * S, nullptr,
        out + so, nullptr, S, 2 * S, D, 0, len, b, 0, 0, 0);
  }
}

// Round 7
// 763.951 us; speedup vs baseline: 1.9246x; 1.1262x over previous
//
#include <hip/hip_runtime.h>

// ---------------------------------------------------------------------------
// Self-attention (B=4, S=4096, D=1024), fp32 in/out.
// Q/K chain precision: projections in dual-bf16 (hi+lo, 3-term MFMA);
// Q,K stored as dual-int8 fixed point (Q=(qh+ql/256)*2^-4); QK^T in int8
// MFMA (16x16x64, 2x bf16 rate) with 2 exact i32 accumulators:
//   logit = 2^-8*(acc_hh + acc_cross/256),  acc_cross = qh*kl + ql*kh.
// Noise budget: dropped ql*kl + quant rounding ~0.013 logits << 0.1 flip thr.
// V / PV single-bf16. R7: QK^T -> i8 (2x); Q+K proj un-merged (R6 z-merge
// regressed: 206 vs 192 us, occupancy 17% vs 22%).
// ---------------------------------------------------------------------------

typedef __attribute__((ext_vector_type(4))) float floatx4;
typedef __attribute__((ext_vector_type(4))) int intx4;
typedef __attribute__((ext_vector_type(8))) short shortx8;
typedef unsigned short ushort_t;

__device__ __forceinline__ ushort_t f2bf(float f) {
  union { float f; unsigned u; } x; x.f = f;
  unsigned r = x.u + 0x7fffu + ((x.u >> 16) & 1u);  // RNE
  return (ushort_t)(r >> 16);
}
__device__ __forceinline__ float bf2f(ushort_t h) {
  union { unsigned u; float f; } x; x.u = ((unsigned)h) << 16; return x.f;
}
// fixed-point dual-int8 quant: v ~= (qh + ql/256) / 16
__device__ __forceinline__ void quant8(float v, char& qh, char& ql) {
  float vs = v * 16.0f;
  float h = rintf(vs);
  h = fminf(fmaxf(h, -127.f), 127.f);
  float l = rintf((vs - h) * 256.0f);
  l = fminf(fmaxf(l, -127.f), 127.f);
  qh = (char)(int)h; ql = (char)(int)l;
}

// Async global->LDS, 16B per lane (m97 lever). LDS dest = wave-uniform base
// + lane*16 (m104/m108); lane->LDS mapping contiguous in lane order.
__device__ __forceinline__ void gload_lds16(const void* g, void* l) {
  __builtin_amdgcn_global_load_lds(
      (__attribute__((address_space(1))) void*)(uintptr_t)g,
      (__attribute__((address_space(3))) void*)(unsigned)(uintptr_t)l,
      16, 0, 0);
}

// ---------------- bf16 GEMM (proj / PV): C = A * B^T -----------------------
// Tile BM=TM*32 x BN=TN*32, 256 threads = 4 waves 2x2.
// OMODE: 0 = C fp32 [z*sC+row*ldc+col]; 2 = C bf16 per-batch transposed
//        [(row>>12)*bstride+col*ldc+(row&4095)]; 3 = C int8 pair (quant8).
// LMODE: 0 none; 2 kend=roundup(sent(b0+z),128) (PV);
//        3 skip block if (row0&4095)>=roundup(sent(row0>>12),128) (K/V proj)
template<int TM, int TN, int NA, int NB, int OMODE, int LMODE>
__global__ __launch_bounds__(256)
void gemm_bt(const ushort_t* __restrict__ A0g, const ushort_t* __restrict__ A1g,
             const ushort_t* __restrict__ B0g, const ushort_t* __restrict__ B1g,
             void* __restrict__ C0v, void* __restrict__ C1v,
             int K, int lda, int ldc, long bstride,
             const int* __restrict__ lenp, int b0, long sA, long sB, long sC)
{
  constexpr int BM = TM * 32, BN = TN * 32;
  constexpr int LA = TM / 2, LB = TN / 2;
  constexpr bool DUAL = (NA == 2) && (NB == 2);
  __shared__ ushort_t As[NA][BM][32];
  __shared__ ushort_t Bs[NB][BN][32];

  const int tid = threadIdx.x;
  const int z = blockIdx.z;
  const long row0 = (long)blockIdx.x * BM;
  const long col0 = (long)blockIdx.y * BN;

  int kend = K;
  if constexpr (LMODE == 2) {
    const int sent = lenp[b0 + z] * 2;
    kend = (sent + 127) & ~127;
  } else if constexpr (LMODE == 3) {
    const int sent = lenp[row0 >> 12] * 2;
    if ((int)(row0 & 4095) >= ((sent + 127) & ~127)) return;
  }

  const int sr = tid >> 2, scol = (tid & 3) * 8;
  const ushort_t* pA0 = A0g + z * sA + (row0 + sr) * (long)lda + scol;
  const ushort_t* pA1 = (NA == 2) ? A1g + z * sA + (row0 + sr) * (long)lda + scol : nullptr;
  const ushort_t* pB0 = B0g + z * sB + (col0 + sr) * (long)K + scol;
  const ushort_t* pB1 = (NB == 2) ? B1g + z * sB + (col0 + sr) * (long)K + scol : nullptr;
  ushort_t* lA0 = &As[0][sr][scol];
  ushort_t* lA1 = (NA == 2) ? &As[NA - 1][sr][scol] : nullptr;
  ushort_t* lB0 = &Bs[0][sr][scol];
  ushort_t* lB1 = (NB == 2) ? &Bs[NB - 1][sr][scol] : nullptr;
  const long jA = 64 * (long)lda, jB = 64 * (long)K;

  const int wid = tid >> 6, lane = tid & 63;
  const int wm = (wid >> 1) * (BM / 2), wn = (wid & 1) * (BN / 2);
  const int lr = lane & 15, lq = lane >> 4;

  floatx4 acc[TM][TN] = {};

  for (int k0 = 0; k0 < kend; k0 += 32) {
#pragma unroll
    for (int j = 0; j < LA; ++j) {
      gload_lds16(pA0 + k0 + j * jA, lA0 + j * 2048);
      if constexpr (NA == 2) gload_lds16(pA1 + k0 + j * jA, lA1 + j * 2048);
    }
#pragma unroll
    for (int j = 0; j < LB; ++j) {
      gload_lds16(pB0 + k0 + j * jB, lB0 + j * 2048);
      if constexpr (NB == 2) gload_lds16(pB1 + k0 + j * jB, lB1 + j * 2048);
    }
    __syncthreads();

    shortx8 ah[TM], al[TM], bh[TN], bl[TN];
#pragma unroll
    for (int t = 0; t < TM; ++t) {
      ah[t] = *(const shortx8*)&As[0][wm + t * 16 + lr][lq * 8];
      if constexpr (NA == 2) al[t] = *(const shortx8*)&As[1][wm + t * 16 + lr][lq * 8];
    }
#pragma unroll
    for (int t = 0; t < TN; ++t) {
      bh[t] = *(const shortx8*)&Bs[0][wn + t * 16 + lr][lq * 8];
      if constexpr (NB == 2) bl[t] = *(const shortx8*)&Bs[1][wn + t * 16 + lr][lq * 8];
    }
#pragma unroll
    for (int mt = 0; mt < TM; ++mt)
#pragma unroll
      for (int nt = 0; nt < TN; ++nt) {
        acc[mt][nt] = __builtin_amdgcn_mfma_f32_16x16x32_bf16(ah[mt], bh[nt], acc[mt][nt], 0, 0, 0);
        if constexpr (DUAL) {
          acc[mt][nt] = __builtin_amdgcn_mfma_f32_16x16x32_bf16(ah[mt], bl[nt], acc[mt][nt], 0, 0, 0);
          acc[mt][nt] = __builtin_amdgcn_mfma_f32_16x16x32_bf16(al[mt], bh[nt], acc[mt][nt], 0, 0, 0);
        }
      }
    __syncthreads();
  }

  // C/D layout (m89/m91): col = lane&15, row = (lane>>4)*4 + reg
#pragma unroll
  for (int mt = 0; mt < TM; ++mt) {
#pragma unroll
    for (int nt = 0; nt < TN; ++nt) {
      long col = col0 + wn + nt * 16 + lr;
      if constexpr (OMODE == 2) {
        long row = row0 + wm + mt * 16 + lq * 4;
        long bb = row >> 12, s = row & 4095;
        ushort4 pk;
        pk.x = f2bf(acc[mt][nt][0]); pk.y = f2bf(acc[mt][nt][1]);
        pk.z = f2bf(acc[mt][nt][2]); pk.w = f2bf(acc[mt][nt][3]);
        *(ushort4*)&((ushort_t*)C0v)[bb * bstride + col * ldc + s] = pk;
      } else {
#pragma unroll
        for (int r = 0; r < 4; ++r) {
          long row = row0 + wm + mt * 16 + lq * 4 + r;
          float v = acc[mt][nt][r];
          if constexpr (OMODE == 0) {
            ((float*)C0v)[z * sC + row * ldc + col] = v;
          } else {   // OMODE 3: dual-int8
            char qh, ql;
            quant8(v, qh, ql);
            ((char*)C0v)[row * ldc + col] = qh;
            ((char*)C1v)[row * ldc + col] = ql;
          }
        }
      }
    }
  }
}

// ---------------- int8 QK^T: sc = (Qh+Ql/256)(Kh+Kl/256)^T / 256 ----------
// Tile 128x64, K=1024. 2 i32 accumulators: hh and cross (qh*kl + ql*kh).
__global__ __launch_bounds__(256)
void qk_i8(const char* __restrict__ Qh, const char* __restrict__ Ql,
           const char* __restrict__ Kh, const char* __restrict__ Kl,
           float* __restrict__ sc, const int* __restrict__ lenp, int b)
{
  __shared__ char As[2][128][64];
  __shared__ char Bs[2][64][64];
  const int tid = threadIdx.x;
  const long row0 = (long)blockIdx.x * 128;
  const long col0 = (long)blockIdx.y * 64;
  const int sent = lenp[b] * 2;
  if (col0 >= sent) return;

  const int sr = tid >> 2, sc16 = (tid & 3) * 16;
  const char* pA0 = Qh + (row0 + sr) * 1024 + sc16;
  const char* pA1 = Ql + (row0 + sr) * 1024 + sc16;
  const char* pB0 = Kh + (col0 + sr) * 1024 + sc16;
  const char* pB1 = Kl + (col0 + sr) * 1024 + sc16;
  char* lA0 = &As[0][sr][sc16];
  char* lA1 = &As[1][sr][sc16];
  char* lB0 = &Bs[0][sr][sc16];
  char* lB1 = &Bs[1][sr][sc16];

  const int wid = tid >> 6, lane = tid & 63;
  const int wm = (wid >> 1) * 64, wn = (wid & 1) * 32;
  const int lr = lane & 15, lq = lane >> 4;

  intx4 acc1[4][2] = {};   // qh*kh
  intx4 acc2[4][2] = {};   // qh*kl + ql*kh (shared scale /256)

  for (int k0 = 0; k0 < 1024; k0 += 64) {
#pragma unroll
    for (int j = 0; j < 2; ++j) {
      gload_lds16(pA0 + k0 + j * 65536, lA0 + j * 4096);
      gload_lds16(pA1 + k0 + j * 65536, lA1 + j * 4096);
    }
    gload_lds16(pB0 + k0, lB0);
    gload_lds16(pB1 + k0, lB1);
    __syncthreads();

    intx4 ah[4], al[4], bh[2], bl[2];
#pragma unroll
    for (int t = 0; t < 4; ++t) {
      ah[t] = *(const intx4*)&As[0][wm + t * 16 + lr][lq * 16];
      al[t] = *(const intx4*)&As[1][wm + t * 16 + lr][lq * 16];
    }
#pragma unroll
    for (int t = 0; t < 2; ++t) {
      bh[t] = *(const intx4*)&Bs[0][wn + t * 16 + lr][lq * 16];
      bl[t] = *(const intx4*)&Bs[1][wn + t * 16 + lr][lq * 16];
    }
#pragma unroll
    for (int mt = 0; mt < 4; ++mt)
#pragma unroll
      for (int nt = 0; nt < 2; ++nt) {
        acc1[mt][nt] = __builtin_amdgcn_mfma_i32_16x16x64_i8(ah[mt], bh[nt], acc1[mt][nt], 0, 0, 0);
        acc2[mt][nt] = __builtin_amdgcn_mfma_i32_16x16x64_i8(ah[mt], bl[nt], acc2[mt][nt], 0, 0, 0);
        acc2[mt][nt] = __builtin_amdgcn_mfma_i32_16x16x64_i8(al[mt], bh[nt], acc2[mt][nt], 0, 0, 0);
      }
    __syncthreads();
  }

#pragma unroll
  for (int mt = 0; mt < 4; ++mt)
#pragma unroll
    for (int nt = 0; nt < 2; ++nt) {
      long col = col0 + wn + nt * 16 + lr;
#pragma unroll
      for (int r = 0; r < 4; ++r) {
        long row = row0 + wm + mt * 16 + lq * 4 + r;
        float v = ((float)acc1[mt][nt][r] + (float)acc2[mt][nt][r] * (1.0f / 256.0f))
                  * (1.0f / 256.0f);
        sc[row * 4096 + col] = v;
      }
    }
}

__global__ __launch_bounds__(256)
void cast_split(const float* __restrict__ in, ushort_t* __restrict__ hi,
                ushort_t* __restrict__ lo, int n4) {
  int i = blockIdx.x * 256 + threadIdx.x;
  if (i < n4) {
    float4 v = ((const float4*)in)[i];
    ushort4 h, l;
    h.x = f2bf(v.x); l.x = f2bf(v.x - bf2f(h.x));
    h.y = f2bf(v.y); l.y = f2bf(v.y - bf2f(h.y));
    h.z = f2bf(v.z); l.z = f2bf(v.z - bf2f(h.z));
    h.w = f2bf(v.w); l.w = f2bf(v.w - bf2f(h.w));
    ((ushort4*)hi)[i] = h;
    ((ushort4*)lo)[i] = l;
  }
}

__global__ __launch_bounds__(256)
void cast_w3(const float* __restrict__ w0, const float* __restrict__ w1,
             const float* __restrict__ w2, ushort_t* __restrict__ h0,
             ushort_t* __restrict__ l0, ushort_t* __restrict__ h1,
             ushort_t* __restrict__ l1, ushort_t* __restrict__ h2,
             ushort_t* __restrict__ l2, int n4) {
  int i = blockIdx.x * 256 + threadIdx.x;
  if (i >= n4) return;
  const float* in = (blockIdx.y == 0) ? w0 : (blockIdx.y == 1) ? w1 : w2;
  ushort_t* hi = (blockIdx.y == 0) ? h0 : (blockIdx.y == 1) ? h1 : h2;
  ushort_t* lo = (blockIdx.y == 0) ? l0 : (blockIdx.y == 1) ? l1 : l2;
  float4 v = ((const float4*)in)[i];
  ushort4 h, l;
  h.x = f2bf(v.x); l.x = f2bf(v.x - bf2f(h.x));
  h.y = f2bf(v.y); l.y = f2bf(v.y - bf2f(h.y));
  h.z = f2bf(v.z); l.z = f2bf(v.z - bf2f(h.z));
  h.w = f2bf(v.w); l.w = f2bf(v.w - bf2f(h.w));
  ((ushort4*)hi)[i] = h;
  ((ushort4*)lo)[i] = l;
}

// Masked softmax; reads fp32 row, writes bf16 P into the first half in place.
__global__ __launch_bounds__(256)
void softmax_rows(float* __restrict__ scores, const int* __restrict__ length, int b0) {
  const long row = blockIdx.x;
  const int b = b0 + (int)(row >> 12);
  float* p = scores + row * 4096;
  const int sent = length[b] * 2;
  const int sentceil = (sent + 127) & ~127;
  const int tid = threadIdx.x;
  float vals[16];
  float mx = -3.4e38f;
  int nj = 0;
  for (int c = tid; c < sentceil; c += 256) {
    float v = p[c];
    v = (c < sent) ? v : -2147483648.0f;   // NEG_BIG
    vals[nj++] = v;
    mx = fmaxf(mx, v);
  }
#pragma unroll
  for (int off = 32; off > 0; off >>= 1) mx = fmaxf(mx, __shfl_down(mx, off));
  __shared__ float red[8];
  if ((tid & 63) == 0) red[tid >> 6] = mx;
  __syncthreads();
  mx = fmaxf(fmaxf(red[0], red[1]), fmaxf(red[2], red[3]));
  float sum = 0.f;
  for (int j = 0; j < nj; ++j) { vals[j] = __expf(vals[j] - mx); sum += vals[j]; }
#pragma unroll
  for (int off = 32; off > 0; off >>= 1) sum += __shfl_down(sum, off);
  __syncthreads();
  if ((tid & 63) == 0) red[tid >> 6] = sum;
  __syncthreads();
  float inv = 1.0f / (red[0] + red[1] + red[2] + red[3]);
  ushort_t* pb = (ushort_t*)p;
  int j = 0;
  for (int c = tid; c < sentceil; c += 256) pb[c] = f2bf(vals[j++] * inv);
}

extern "C" void kernel_launch(void* const* d_in, const int* in_sizes, int n_in,
                              void* d_out, int out_size, void* d_ws, size_t ws_size,
                              hipStream_t stream) {
  const float* X   = (const float*)d_in[0];
  const int*   len = (const int*)d_in[1];
  const float* Wq  = (const float*)d_in[2];
  const float* Wk  = (const float*)d_in[3];
  const float* Wv  = (const float*)d_in[4];
  float* out = (float*)d_out;

  const int Bn = 4, S = 4096, D = 1024;
  const long MS = (long)Bn * S;

  char* w = (char*)d_ws;
  ushort_t* Xhi = (ushort_t*)w; w += MS * D * 2;   // dead after proj (sc alias)
  ushort_t* Xlo = (ushort_t*)w; w += MS * D * 2;
  char* Qh8 = w; w += MS * D;
  char* Ql8 = w; w += MS * D;
  char* Kh8 = w; w += MS * D;
  char* Kl8 = w; w += MS * D;
  ushort_t* Vt  = (ushort_t*)w; w += MS * D * 2;   // bf16 [B][D][S]
  ushort_t* Wqh = (ushort_t*)w; w += (long)D * D * 2;
  ushort_t* Wql = (ushort_t*)w; w += (long)D * D * 2;
  ushort_t* Wkh = (ushort_t*)w; w += (long)D * D * 2;
  ushort_t* Wkl = (ushort_t*)w; w += (long)D * D * 2;
  ushort_t* Wvh = (ushort_t*)w; w += (long)D * D * 2;
  ushort_t* Wvl = (ushort_t*)w; w += (long)D * D * 2;
  float* sc = (float*)d_ws;                        // aliases Xhi/Xlo (64<67MB)

  const int n4w = D * D / 4;
  cast_split<<<(int)(MS * D / 4 + 255) / 256, 256, 0, stream>>>(X, Xhi, Xlo, (int)(MS * D / 4));
  cast_w3<<<dim3((n4w + 255) / 256, 3), 256, 0, stream>>>(
      Wq, Wk, Wv, Wqh, Wql, Wkh, Wkl, Wvh, Wvl, n4w);

  dim3 blk(256);
  dim3 gproj(MS / 128, D / 128, 1);
  // Q proj (all rows) -> int8 pair
  gemm_bt<4, 4, 2, 2, 3, 0><<<gproj, blk, 0, stream>>>(
      Xhi, Xlo, Wqh, Wql, Qh8, Ql8, D, D, D, 0, len, 0, 0, 0, 0);
  // K proj (row-skip) -> int8 pair
  gemm_bt<4, 4, 2, 2, 3, 3><<<gproj, blk, 0, stream>>>(
      Xhi, Xlo, Wkh, Wkl, Kh8, Kl8, D, D, D, 0, len, 0, 0, 0, 0);
  // V proj (row-skip) -> bf16 transposed
  gemm_bt<4, 4, 1, 1, 2, 3><<<gproj, blk, 0, stream>>>(
      Xhi, nullptr, Wvh, nullptr, Vt, nullptr, D, D, S, (long)D * S,
      len, 0, 0, 0, 0);

  for (int b = 0; b < Bn; ++b) {
    const long so = (long)b * S * D;
    qk_i8<<<dim3(S / 128, S / 64), blk, 0, stream>>>(
        Qh8 + so, Ql8 + so, Kh8 + so, Kl8 + so, sc, len, b);
    softmax_rows<<<S, 256, 0, stream>>>(sc, len, b);
    gemm_bt<4, 2, 1, 1, 0, 2><<<dim3(S / 128, D / 64, 1), blk, 0, stream>>>(
        (const ushort_t*)sc, nullptr, Vt + (long)b * D * S, nullptr,
        out + so, nullptr, S, 2 * S, D, 0, len, b, 0, 0, 0);
  }
}